// Round 1
// baseline (1544.940 us; speedup 1.0000x reference)
//
#include <hip/hip_runtime.h>
#include <hip/hip_bf16.h>

// TreeNet: T=512 nodes, B=256 batch, D=256 dim, BF=2 branching.
// Decomposition:
//   K0  stack simulation (int only) -> child lists / worklists
//   K1  H = inputs @ W_in + b            (parallel GEMM, into memory region)
//   K2a G[t] += tanh(H[leaf_child]) @ W_ch[i]   (parallel gather-GEMM, x2 lists)
//   K2b memory[leaf] = tanh(H[leaf])     (parallel elementwise)
//   K3  sequential per-batch chain over combine->combine edges (W in VGPRs)
//   K4  out[k] = memory[root[k], k]
//
// R1 changes vs previous best (1075 us):
//   k_seq: raw s_barrier + lgkmcnt-only waits (no vmcnt(0) drain per step),
//          G-row prefetched one chain-step ahead, launch_bounds(512,2) so
//          w[128] is truly VGPR-resident (old VGPR_Count=88 proved it wasn't).
//   k_gemm_h/k_leafgemm: contiguous col mapping -> ds_read_b128 everywhere,
//          dwordx4 stores/RMW, register prefetch pipeline with non-draining
//          barriers. FP per-element summation order unchanged (bitwise-same
//          results as previous kernel).

constexpr int T = 512, B = 256, D = 256;

// ws layout in u32 units
constexpr int WS_CNT  = 0;        // [2] atomic counters for leaf lists
constexpr int WS_ROOT = 16;       // [256]
constexpr int WS_NW   = 272;      // [256]
constexpr int WS_L0   = 1024;     // [131072] leaf-child entries, i=0
constexpr int WS_L1   = WS_L0 + T * B;     // [131072] i=1
constexpr int WS_WORK = WS_L1 + T * B;     // [256*1024] per-k combine worklist

// ---------------- K0: stack simulation ----------------
__global__ __launch_bounds__(256) void k_stack(const int* __restrict__ ar,
                                               unsigned* __restrict__ ws) {
  __shared__ int ar_l[T];
  __shared__ int S[1024];          // stack ring buffer (mask 1023), write-through
  __shared__ unsigned lbuf0[T];
  __shared__ unsigned lbuf1[T];
  __shared__ unsigned wbuf[1024];
  __shared__ int cnts[4];          // n0, n1, nw, root
  __shared__ unsigned base0, base1;

  int k = blockIdx.x;
  int tid = threadIdx.x;
  ar_l[tid]       = ar[tid * B + k];
  ar_l[tid + 256] = ar[(tid + 256) * B + k];
  S[tid] = 0; S[tid + 256] = 0; S[tid + 512] = 0; S[tid + 768] = 0;
  __syncthreads();

  if (tid == 0) {
    int ptr = 1;           // BF-1
    int top = 0, next = 0; // register cache of S[ptr], S[ptr-1]
    int n0 = 0, n1 = 0, nw = 0;
    for (int t = 0; t < T; t++) {
      int a = ar_l[t];
      int aa = a < 0 ? -a : a;
      unsigned cc[2]; int ncc = 0;
      if (a > 0) {
        int c0 = top;
        if (ar_l[c0] <= 0)
          lbuf0[n0++] = (unsigned)c0 | ((unsigned)t << 9) | ((unsigned)k << 18);
        else
          cc[ncc++] = (unsigned)c0;                 // child slot 0 -> W_ch[0]
        if (a > 1) {
          int c1 = next;
          if (ar_l[c1] <= 0)
            lbuf1[n1++] = (unsigned)c1 | ((unsigned)t << 9) | ((unsigned)k << 18);
          else
            cc[ncc++] = (unsigned)c1 | (1u << 18);  // child slot 1 -> W_ch[1]
        }
      }
      if (a >= 1) {  // combine node: K3 must finalize (tanh) it
        if (ncc == 0) {
          wbuf[nw++] = (unsigned)t | (1u << 19) | (1u << 20);
        } else {
          for (int e = 0; e < ncc; e++) {
            unsigned w = (unsigned)t | ((cc[e] & 511u) << 9) |
                         (((cc[e] >> 18) & 1u) << 18) | (1u << 21);
            if (e == 0) w |= (1u << 19);
            if (e == ncc - 1) w |= (1u << 20);
            wbuf[nw++] = w;
          }
        }
      }
      int pnew = ptr - aa + 1;
      if (a != -1) {
        S[pnew & 1023] = t;                 // write-through
        if (aa == 0)      { next = top; top = t; }
        else if (aa == 1) { top = t; }
        else              { top = t; next = S[(pnew - 1) & 1023]; } // refill
      }
      ptr = pnew;
    }
    cnts[0] = n0; cnts[1] = n1; cnts[2] = nw;
    cnts[3] = S[ptr & 1023];
    base0 = atomicAdd(ws + WS_CNT + 0, (unsigned)n0);
    base1 = atomicAdd(ws + WS_CNT + 1, (unsigned)n1);
  }
  __syncthreads();
  int n0 = cnts[0], n1 = cnts[1], nw = cnts[2];
  for (int i = tid; i < n0; i += 256) ws[WS_L0 + base0 + i] = lbuf0[i];
  for (int i = tid; i < n1; i += 256) ws[WS_L1 + base1 + i] = lbuf1[i];
  for (int i = tid; i < nw; i += 256) ws[WS_WORK + k * 1024 + i] = wbuf[i];
  if (tid == 0) { ws[WS_NW + k] = (unsigned)nw; ws[WS_ROOT + k] = (unsigned)cnts[3]; }
}

// ---------------- K1: H = X @ W_in + b ----------------
// 64-row x 256-col tile per wg; thread = 8x8 register tile.
// Cols per thread: {cq*4+q} and {128+cq*4+q} -> all LDS reads are b128,
// all global stores are dwordx4. Register prefetch over single LDS buffer.
__global__ __launch_bounds__(256, 3) void k_gemm_h(const float* __restrict__ X,
                                                   const float* __restrict__ W,
                                                   const float* __restrict__ bias,
                                                   float* __restrict__ Hm) {
  int row0 = blockIdx.x * 64;
  __shared__ __align__(16) float As[16][72];   // [k][row], 288B row stride
  __shared__ __align__(16) float Bs[16][256];  // [k][col]
  int tid = threadIdx.x;
  int cq = tid & 31, rg = tid >> 5;
  float acc[8][8];
  float4 b_lo = *(const float4*)&bias[cq * 4];
  float4 b_hi = *(const float4*)&bias[128 + cq * 4];
#pragma unroll
  for (int rr = 0; rr < 8; rr++) {
    acc[rr][0] = b_lo.x; acc[rr][1] = b_lo.y; acc[rr][2] = b_lo.z; acc[rr][3] = b_lo.w;
    acc[rr][4] = b_hi.x; acc[rr][5] = b_hi.y; acc[rr][6] = b_hi.z; acc[rr][7] = b_hi.w;
  }
  int sr = tid >> 2;           // staging row 0..63
  int skc = (tid & 3) * 4;     // staging k-offset
  float4 pa;
  float4 pb[4];
  pa = *(const float4*)&X[(row0 + sr) * 256 + skc];
#pragma unroll
  for (int i = 0; i < 4; i++) {
    int idx = tid + i * 256;
    int r = idx >> 6, c4 = idx & 63;
    pb[i] = *(const float4*)&W[r * 256 + c4 * 4];
  }
  for (int kk = 0; kk < 256; kk += 16) {
    // regs -> LDS (compiler inserts vmcnt waits here)
    As[skc + 0][sr] = pa.x; As[skc + 1][sr] = pa.y;
    As[skc + 2][sr] = pa.z; As[skc + 3][sr] = pa.w;
#pragma unroll
    for (int i = 0; i < 4; i++) {
      int idx = tid + i * 256;
      int r = idx >> 6, c4 = idx & 63;
      *(float4*)&Bs[r][c4 * 4] = pb[i];
    }
    __builtin_amdgcn_sched_barrier(0);
    asm volatile("s_waitcnt lgkmcnt(0)" ::: "memory");
    __builtin_amdgcn_s_barrier();                 // no vmcnt drain
    __builtin_amdgcn_sched_barrier(0);
    if (kk + 16 < 256) {  // prefetch next panel under this panel's FMAs
      pa = *(const float4*)&X[(row0 + sr) * 256 + kk + 16 + skc];
#pragma unroll
      for (int i = 0; i < 4; i++) {
        int idx = tid + i * 256;
        int r = idx >> 6, c4 = idx & 63;
        pb[i] = *(const float4*)&W[(kk + 16 + r) * 256 + c4 * 4];
      }
    }
#pragma unroll
    for (int kc = 0; kc < 16; kc++) {
      float4 a0  = *(const float4*)&As[kc][rg * 8];       // broadcast b128
      float4 a1  = *(const float4*)&As[kc][rg * 8 + 4];
      float4 blo = *(const float4*)&Bs[kc][cq * 4];       // consecutive b128
      float4 bhi = *(const float4*)&Bs[kc][128 + cq * 4];
      float a[8]  = {a0.x, a0.y, a0.z, a0.w, a1.x, a1.y, a1.z, a1.w};
      float bb[8] = {blo.x, blo.y, blo.z, blo.w, bhi.x, bhi.y, bhi.z, bhi.w};
#pragma unroll
      for (int rr = 0; rr < 8; rr++)
#pragma unroll
        for (int q = 0; q < 8; q++) acc[rr][q] += a[rr] * bb[q];
    }
    __builtin_amdgcn_sched_barrier(0);
    __builtin_amdgcn_s_barrier();                 // protect LDS overwrite
    __builtin_amdgcn_sched_barrier(0);
  }
#pragma unroll
  for (int rr = 0; rr < 8; rr++) {
    float4 lo, hi;
    lo.x = acc[rr][0]; lo.y = acc[rr][1]; lo.z = acc[rr][2]; lo.w = acc[rr][3];
    hi.x = acc[rr][4]; hi.y = acc[rr][5]; hi.z = acc[rr][6]; hi.w = acc[rr][7];
    float* dst = &Hm[(row0 + rg * 8 + rr) * 256];
    *(float4*)&dst[cq * 4] = lo;
    *(float4*)&dst[128 + cq * 4] = hi;
  }
}

// ---------------- K2a: gather-GEMM of leaf-child contributions ----------------
__global__ __launch_bounds__(256, 3) void k_leafgemm(const float* __restrict__ Hm,
                                                     float* __restrict__ Gm,
                                                     const float* __restrict__ Wch,
                                                     const unsigned* __restrict__ list,
                                                     const unsigned* __restrict__ cntp,
                                                     int which) {
  unsigned cnt = *cntp;
  unsigned tile0 = blockIdx.x * 64;
  if (tile0 >= cnt) return;
  int ne = (int)min(64u, cnt - tile0);
  __shared__ unsigned ent[64];
  __shared__ __align__(16) float As[16][72];
  __shared__ __align__(16) float Bs[16][256];
  int tid = threadIdx.x;
  if (tid < 64) ent[tid] = (tid < ne) ? list[tile0 + tid] : 0u;
  __syncthreads();
  const float* W = Wch + which * (D * D);
  int cq = tid & 31, rg = tid >> 5;
  float acc[8][8];
#pragma unroll
  for (int rr = 0; rr < 8; rr++)
#pragma unroll
    for (int q = 0; q < 8; q++) acc[rr][q] = 0.0f;
  int sr = tid >> 2;
  int skc = (tid & 3) * 4;
  unsigned se = ent[sr];
  int sc = (int)(se & 511u), skb = (int)((se >> 18) & 255u);
  const float* srow = &Hm[((sc << 8) + skb) * 256];
  float4 pa; pa.x = pa.y = pa.z = pa.w = 0.0f;
  float4 pb[4];
  if (sr < ne) pa = *(const float4*)&srow[skc];
#pragma unroll
  for (int i = 0; i < 4; i++) {
    int idx = tid + i * 256;
    int r = idx >> 6, c4 = idx & 63;
    pb[i] = *(const float4*)&W[r * 256 + c4 * 4];
  }
  for (int kk = 0; kk < 256; kk += 16) {
    As[skc + 0][sr] = tanhf(pa.x); As[skc + 1][sr] = tanhf(pa.y);
    As[skc + 2][sr] = tanhf(pa.z); As[skc + 3][sr] = tanhf(pa.w);
#pragma unroll
    for (int i = 0; i < 4; i++) {
      int idx = tid + i * 256;
      int r = idx >> 6, c4 = idx & 63;
      *(float4*)&Bs[r][c4 * 4] = pb[i];
    }
    __builtin_amdgcn_sched_barrier(0);
    asm volatile("s_waitcnt lgkmcnt(0)" ::: "memory");
    __builtin_amdgcn_s_barrier();
    __builtin_amdgcn_sched_barrier(0);
    if (kk + 16 < 256) {
      if (sr < ne) pa = *(const float4*)&srow[kk + 16 + skc];
#pragma unroll
      for (int i = 0; i < 4; i++) {
        int idx = tid + i * 256;
        int r = idx >> 6, c4 = idx & 63;
        pb[i] = *(const float4*)&W[(kk + 16 + r) * 256 + c4 * 4];
      }
    }
#pragma unroll
    for (int kc = 0; kc < 16; kc++) {
      float4 a0  = *(const float4*)&As[kc][rg * 8];
      float4 a1  = *(const float4*)&As[kc][rg * 8 + 4];
      float4 blo = *(const float4*)&Bs[kc][cq * 4];
      float4 bhi = *(const float4*)&Bs[kc][128 + cq * 4];
      float a[8]  = {a0.x, a0.y, a0.z, a0.w, a1.x, a1.y, a1.z, a1.w};
      float bb[8] = {blo.x, blo.y, blo.z, blo.w, bhi.x, bhi.y, bhi.z, bhi.w};
#pragma unroll
      for (int rr = 0; rr < 8; rr++)
#pragma unroll
        for (int q = 0; q < 8; q++) acc[rr][q] += a[rr] * bb[q];
    }
    __builtin_amdgcn_sched_barrier(0);
    __builtin_amdgcn_s_barrier();
    __builtin_amdgcn_sched_barrier(0);
  }
#pragma unroll
  for (int rr = 0; rr < 8; rr++) {
    int e = rg * 8 + rr;
    if (e < ne) {
      unsigned en = ent[e];
      int t = (int)((en >> 9) & 511u), kb = (int)((en >> 18) & 255u);
      float* dst = &Gm[((t << 8) + kb) * 256];
      float4 lo = *(const float4*)&dst[cq * 4];
      float4 hi = *(const float4*)&dst[128 + cq * 4];
      lo.x += acc[rr][0]; lo.y += acc[rr][1]; lo.z += acc[rr][2]; lo.w += acc[rr][3];
      hi.x += acc[rr][4]; hi.y += acc[rr][5]; hi.z += acc[rr][6]; hi.w += acc[rr][7];
      *(float4*)&dst[cq * 4] = lo;
      *(float4*)&dst[128 + cq * 4] = hi;
    }
  }
}

// ---------------- K2b: tanh leaves in place ----------------
__global__ __launch_bounds__(256) void k_leaftanh(const int* __restrict__ ar,
                                                  float* __restrict__ Mm) {
  int r0 = blockIdx.x * 64;  // row = t*B + k  == flat index into ar
  __shared__ int lar[64];
  int tid = threadIdx.x;
  if (tid < 64) lar[tid] = ar[r0 + tid];
  __syncthreads();
  for (int r = 0; r < 64; r++) {
    if (lar[r] <= 0) {
      float v = Mm[(r0 + r) * 256 + tid];
      Mm[(r0 + r) * 256 + tid] = tanhf(v);
    }
  }
}

// ---------------- K3: sequential combine chain, one wg per batch ----------------
// 512 threads: thread (j = tid&255, h = tid>>8) holds W_ch[1][h*128..+127][j]
// in 128 VGPRs (launch_bounds(512,2) raises VGPR cap to 256 so it fits).
// Per chain step: only lgkmcnt-draining raw barriers (the Mm store and the
// prefetched next-step G-row stay in flight across barriers); G-row for step
// n+1 is issued before step n's dot so its latency hides under the FMAs.
__global__ __launch_bounds__(512, 2) void k_seq(float* __restrict__ Mm,
                                                const float* __restrict__ Wch,
                                                const unsigned* __restrict__ ws) {
  int k = blockIdx.x;
  int tid = threadIdx.x;
  int j = tid & 255, h = tid >> 8;
  __shared__ __align__(16) float crow[256];
  __shared__ float partial[256];
  __shared__ int cached;
  if (tid == 0) cached = -1;
  float w[128];
  const float* W1 = Wch + D * D;
#pragma unroll
  for (int p = 0; p < 128; p++) w[p] = W1[(h * 128 + p) * 256 + j];
  int nw = (int)ws[WS_NW + k];
  const unsigned* work = ws + WS_WORK + k * 1024;
  float acc = 0.0f;
  __syncthreads();
  unsigned e = (nw > 0) ? work[0] : 0u;
  float nb = 0.0f;  // prefetched G-row value for the next `first` entry
  if (nw > 0 && ((e >> 19) & 1u) && h == 0)
    nb = Mm[(((int)(e & 511u) << 8) + k) * 256 + j];
  for (int n = 0; n < nw; n++) {
    unsigned cur = e;
    unsigned nxt = (n + 1 < nw) ? work[n + 1] : 0u;
    int t = (int)(cur & 511u), c = (int)((cur >> 9) & 511u);
    int wi = (int)((cur >> 18) & 1u);
    bool first = (cur >> 19) & 1u, last = (cur >> 20) & 1u, hasc = (cur >> 21) & 1u;
    if (first) acc = (h == 0) ? nb : 0.0f;     // consume prefetch
    float nb2 = 0.0f;                           // issue next prefetch early
    if ((n + 1 < nw) && ((nxt >> 19) & 1u) && h == 0)
      nb2 = Mm[(((int)(nxt & 511u) << 8) + k) * 256 + j];
    if (hasc) {
      if (c != cached) {
        // rare generic path: full drain so prior in-flight stores are visible
        asm volatile("s_waitcnt vmcnt(0) lgkmcnt(0)" ::: "memory");
        __builtin_amdgcn_s_barrier();
        __builtin_amdgcn_sched_barrier(0);
        if (tid < 256) crow[tid] = Mm[((c << 8) + k) * 256 + tid];
        if (tid == 0) cached = c;
        asm volatile("s_waitcnt vmcnt(0) lgkmcnt(0)" ::: "memory");
        __builtin_amdgcn_s_barrier();
        __builtin_amdgcn_sched_barrier(0);
      }
      if (wi == 1) {  // fast path: register-resident W_ch[1]
#pragma unroll
        for (int p = 0; p < 32; p++) {
          float4 c4 = ((const float4*)crow)[h * 32 + p];
          acc += c4.x * w[4 * p] + c4.y * w[4 * p + 1] +
                 c4.z * w[4 * p + 2] + c4.w * w[4 * p + 3];
        }
      } else {  // rare: stream W_ch[0] from L2
        const float* W0 = Wch;
#pragma unroll 8
        for (int p = 0; p < 128; p++)
          acc += crow[h * 128 + p] * W0[(h * 128 + p) * 256 + j];
      }
    }
    if (last) {
      if (h == 1) partial[j] = acc;
      __builtin_amdgcn_sched_barrier(0);
      asm volatile("s_waitcnt lgkmcnt(0)" ::: "memory");
      __builtin_amdgcn_s_barrier();               // no vmcnt drain
      __builtin_amdgcn_sched_barrier(0);
      if (h == 0) {
        float v = tanhf(acc + partial[j]);
        Mm[((t << 8) + k) * 256 + j] = v;          // fire-and-forget store
        crow[j] = v;
      }
      if (tid == 0) cached = t;
      __builtin_amdgcn_sched_barrier(0);
      asm volatile("s_waitcnt lgkmcnt(0)" ::: "memory");
      __builtin_amdgcn_s_barrier();               // no vmcnt drain
      __builtin_amdgcn_sched_barrier(0);
    }
    e = nxt; nb = nb2;
  }
}

// ---------------- K4: gather roots ----------------
__global__ __launch_bounds__(256) void k_root(const float* __restrict__ Mm,
                                              float* __restrict__ out,
                                              const unsigned* __restrict__ ws) {
  int k = blockIdx.x;
  unsigned r = ws[WS_ROOT + k];
  out[k * 256 + threadIdx.x] = Mm[(((int)r << 8) + k) * 256 + threadIdx.x];
}

extern "C" void kernel_launch(void* const* d_in, const int* in_sizes, int n_in,
                              void* d_out, int out_size, void* d_ws, size_t ws_size,
                              hipStream_t stream) {
  const float* X    = (const float*)d_in[0];
  const int*   AR   = (const int*)d_in[1];
  const float* Win  = (const float*)d_in[2];
  const float* Wch  = (const float*)d_in[3];
  const float* bias = (const float*)d_in[4];
  float* out = (float*)d_out;
  float* Mm  = out + B * D;  // memory region of output doubles as H/G scratch
  unsigned* ws = (unsigned*)d_ws;

  hipMemsetAsync(d_ws, 0, 512, stream);  // zero atomic counters
  k_stack<<<B, 256, 0, stream>>>(AR, ws);
  k_gemm_h<<<(T * B) / 64, 256, 0, stream>>>(X, Win, bias, Mm);
  k_leafgemm<<<(T * B) / 64, 256, 0, stream>>>(Mm, Mm, Wch, ws + WS_L0, ws + WS_CNT + 0, 0);
  k_leafgemm<<<(T * B) / 64, 256, 0, stream>>>(Mm, Mm, Wch, ws + WS_L1, ws + WS_CNT + 1, 1);
  k_leaftanh<<<(T * B) / 64, 256, 0, stream>>>(AR, Mm);
  k_seq<<<B, 512, 0, stream>>>(Mm, Wch, ws);
  k_root<<<B, 256, 0, stream>>>(Mm, out, ws);
}

// Round 2
// 1041.268 us; speedup vs baseline: 1.4837x; 1.4837x over previous
//
#include <hip/hip_runtime.h>
#include <hip/hip_bf16.h>

// TreeNet: T=512 nodes, B=256 batch, D=256 dim, BF=2 branching.
// Decomposition:
//   K0  stack simulation (int only) -> child lists / worklists
//   K1  H = inputs @ W_in + b; leaf rows (ar<=0) get tanh fused at store
//   K2a G[t] += H[leaf_child] @ W_ch[i]   (leaf rows already tanh'd by K1)
//   K3  sequential per-batch chain over combine->combine edges (W in VGPRs)
//   K4  out[k] = memory[root[k], k]
//
// R2 notes:
//   R1's reg-prefetch GEMM + __launch_bounds__(256,3) capped VGPRs at 84 ->
//   scratch spills (WRITE_SIZE 1.35GB vs 134MB ideal). Reverted to the
//   R0-proven loop structure (plain __syncthreads, no prefetch regs,
//   launch_bounds(256)), keeping only register-neutral wins:
//     - contiguous column remap -> all LDS reads ds_read_b128, stores dwordx4
//       (bitwise-identical results: per-element k-order unchanged)
//     - As pad 65->68: 16B-aligned b128 A-reads, 2-way (free) As writes
//     - leaf tanh fused into K1 epilogue; k_leaftanh kernel deleted;
//       k_leafgemm staging is now a pure copy (no 64x tanhf per thread)
//   k_seq kept from R1 (non-draining barriers + G-row prefetch, (512,2)).

constexpr int T = 512, B = 256, D = 256;

// ws layout in u32 units
constexpr int WS_CNT  = 0;        // [2] atomic counters for leaf lists
constexpr int WS_ROOT = 16;       // [256]
constexpr int WS_NW   = 272;      // [256]
constexpr int WS_L0   = 1024;     // [131072] leaf-child entries, i=0
constexpr int WS_L1   = WS_L0 + T * B;     // [131072] i=1
constexpr int WS_WORK = WS_L1 + T * B;     // [256*1024] per-k combine worklist

// ---------------- K0: stack simulation ----------------
__global__ __launch_bounds__(256) void k_stack(const int* __restrict__ ar,
                                               unsigned* __restrict__ ws) {
  __shared__ int ar_l[T];
  __shared__ int S[1024];          // stack ring buffer (mask 1023), write-through
  __shared__ unsigned lbuf0[T];
  __shared__ unsigned lbuf1[T];
  __shared__ unsigned wbuf[1024];
  __shared__ int cnts[4];          // n0, n1, nw, root
  __shared__ unsigned base0, base1;

  int k = blockIdx.x;
  int tid = threadIdx.x;
  ar_l[tid]       = ar[tid * B + k];
  ar_l[tid + 256] = ar[(tid + 256) * B + k];
  S[tid] = 0; S[tid + 256] = 0; S[tid + 512] = 0; S[tid + 768] = 0;
  __syncthreads();

  if (tid == 0) {
    int ptr = 1;           // BF-1
    int top = 0, next = 0; // register cache of S[ptr], S[ptr-1]
    int n0 = 0, n1 = 0, nw = 0;
    for (int t = 0; t < T; t++) {
      int a = ar_l[t];
      int aa = a < 0 ? -a : a;
      unsigned cc[2]; int ncc = 0;
      if (a > 0) {
        int c0 = top;
        if (ar_l[c0] <= 0)
          lbuf0[n0++] = (unsigned)c0 | ((unsigned)t << 9) | ((unsigned)k << 18);
        else
          cc[ncc++] = (unsigned)c0;                 // child slot 0 -> W_ch[0]
        if (a > 1) {
          int c1 = next;
          if (ar_l[c1] <= 0)
            lbuf1[n1++] = (unsigned)c1 | ((unsigned)t << 9) | ((unsigned)k << 18);
          else
            cc[ncc++] = (unsigned)c1 | (1u << 18);  // child slot 1 -> W_ch[1]
        }
      }
      if (a >= 1) {  // combine node: K3 must finalize (tanh) it
        if (ncc == 0) {
          wbuf[nw++] = (unsigned)t | (1u << 19) | (1u << 20);
        } else {
          for (int e = 0; e < ncc; e++) {
            unsigned w = (unsigned)t | ((cc[e] & 511u) << 9) |
                         (((cc[e] >> 18) & 1u) << 18) | (1u << 21);
            if (e == 0) w |= (1u << 19);
            if (e == ncc - 1) w |= (1u << 20);
            wbuf[nw++] = w;
          }
        }
      }
      int pnew = ptr - aa + 1;
      if (a != -1) {
        S[pnew & 1023] = t;                 // write-through
        if (aa == 0)      { next = top; top = t; }
        else if (aa == 1) { top = t; }
        else              { top = t; next = S[(pnew - 1) & 1023]; } // refill
      }
      ptr = pnew;
    }
    cnts[0] = n0; cnts[1] = n1; cnts[2] = nw;
    cnts[3] = S[ptr & 1023];
    base0 = atomicAdd(ws + WS_CNT + 0, (unsigned)n0);
    base1 = atomicAdd(ws + WS_CNT + 1, (unsigned)n1);
  }
  __syncthreads();
  int n0 = cnts[0], n1 = cnts[1], nw = cnts[2];
  for (int i = tid; i < n0; i += 256) ws[WS_L0 + base0 + i] = lbuf0[i];
  for (int i = tid; i < n1; i += 256) ws[WS_L1 + base1 + i] = lbuf1[i];
  for (int i = tid; i < nw; i += 256) ws[WS_WORK + k * 1024 + i] = wbuf[i];
  if (tid == 0) { ws[WS_NW + k] = (unsigned)nw; ws[WS_ROOT + k] = (unsigned)cnts[3]; }
}

// ---------------- K1: H = X @ W_in + b  (+ fused leaf tanh) ----------------
// 64-row x 256-col tile per wg; thread = 8x8 register tile.
// Cols per thread: {cq*4+q} and {128+cq*4+q} -> LDS reads are b128
// (A reads broadcast, B reads contiguous conflict-free), stores dwordx4.
// R0-proven loop structure: direct global->LDS staging, two __syncthreads.
__global__ __launch_bounds__(256) void k_gemm_h(const float* __restrict__ X,
                                                const float* __restrict__ W,
                                                const float* __restrict__ bias,
                                                const int* __restrict__ ar,
                                                float* __restrict__ Hm) {
  int row0 = blockIdx.x * 64;
  __shared__ __align__(16) float As[16][68];   // [k][row], 272B stride (16B-aligned)
  __shared__ __align__(16) float Bs[16][256];  // [k][col]
  __shared__ int lar[64];
  int tid = threadIdx.x;
  if (tid < 64) lar[tid] = ar[row0 + tid];     // row = t*B+k == flat ar index
  int cq = tid & 31, rg = tid >> 5;
  float acc[8][8];
  float4 b_lo = *(const float4*)&bias[cq * 4];
  float4 b_hi = *(const float4*)&bias[128 + cq * 4];
#pragma unroll
  for (int rr = 0; rr < 8; rr++) {
    acc[rr][0] = b_lo.x; acc[rr][1] = b_lo.y; acc[rr][2] = b_lo.z; acc[rr][3] = b_lo.w;
    acc[rr][4] = b_hi.x; acc[rr][5] = b_hi.y; acc[rr][6] = b_hi.z; acc[rr][7] = b_hi.w;
  }
  int sr = tid >> 2;           // staging row 0..63
  int skc = (tid & 3) * 4;     // staging k-offset
  for (int kk = 0; kk < 256; kk += 16) {
    float4 a4 = *(const float4*)&X[(row0 + sr) * 256 + kk + skc];
    As[skc + 0][sr] = a4.x; As[skc + 1][sr] = a4.y;
    As[skc + 2][sr] = a4.z; As[skc + 3][sr] = a4.w;
#pragma unroll
    for (int i = 0; i < 4; i++) {
      int idx = tid + i * 256;
      int r = idx >> 6, c4 = idx & 63;
      *(float4*)&Bs[r][c4 * 4] = *(const float4*)&W[(kk + r) * 256 + c4 * 4];
    }
    __syncthreads();
#pragma unroll
    for (int kc = 0; kc < 16; kc++) {
      float4 a0  = *(const float4*)&As[kc][rg * 8];       // broadcast b128
      float4 a1  = *(const float4*)&As[kc][rg * 8 + 4];
      float4 blo = *(const float4*)&Bs[kc][cq * 4];       // contiguous b128
      float4 bhi = *(const float4*)&Bs[kc][128 + cq * 4];
      float a[8]  = {a0.x, a0.y, a0.z, a0.w, a1.x, a1.y, a1.z, a1.w};
      float bb[8] = {blo.x, blo.y, blo.z, blo.w, bhi.x, bhi.y, bhi.z, bhi.w};
#pragma unroll
      for (int rr = 0; rr < 8; rr++)
#pragma unroll
        for (int q = 0; q < 8; q++) acc[rr][q] += a[rr] * bb[q];
    }
    __syncthreads();
  }
#pragma unroll
  for (int rr = 0; rr < 8; rr++) {
    int row = rg * 8 + rr;
    bool leaf = lar[row] <= 0;   // leaf (or ignore) node: finalize with tanh
    float4 lo, hi;
    lo.x = acc[rr][0]; lo.y = acc[rr][1]; lo.z = acc[rr][2]; lo.w = acc[rr][3];
    hi.x = acc[rr][4]; hi.y = acc[rr][5]; hi.z = acc[rr][6]; hi.w = acc[rr][7];
    if (leaf) {
      lo.x = tanhf(lo.x); lo.y = tanhf(lo.y); lo.z = tanhf(lo.z); lo.w = tanhf(lo.w);
      hi.x = tanhf(hi.x); hi.y = tanhf(hi.y); hi.z = tanhf(hi.z); hi.w = tanhf(hi.w);
    }
    float* dst = &Hm[(row0 + row) * 256];
    *(float4*)&dst[cq * 4] = lo;
    *(float4*)&dst[128 + cq * 4] = hi;
  }
}

// ---------------- K2a: gather-GEMM of leaf-child contributions ----------------
// Leaf rows were already tanh'd by K1 -> staging is a pure copy.
__global__ __launch_bounds__(256) void k_leafgemm(const float* __restrict__ Hm,
                                                  float* __restrict__ Gm,
                                                  const float* __restrict__ Wch,
                                                  const unsigned* __restrict__ list,
                                                  const unsigned* __restrict__ cntp,
                                                  int which) {
  unsigned cnt = *cntp;
  unsigned tile0 = blockIdx.x * 64;
  if (tile0 >= cnt) return;
  int ne = (int)min(64u, cnt - tile0);
  __shared__ unsigned ent[64];
  __shared__ __align__(16) float As[16][68];
  __shared__ __align__(16) float Bs[16][256];
  int tid = threadIdx.x;
  if (tid < 64) ent[tid] = (tid < ne) ? list[tile0 + tid] : 0u;
  __syncthreads();
  const float* W = Wch + which * (D * D);
  int cq = tid & 31, rg = tid >> 5;
  float acc[8][8];
#pragma unroll
  for (int rr = 0; rr < 8; rr++)
#pragma unroll
    for (int q = 0; q < 8; q++) acc[rr][q] = 0.0f;
  int sr = tid >> 2;
  int skc = (tid & 3) * 4;
  unsigned se = ent[sr];
  int sc = (int)(se & 511u), skb = (int)((se >> 18) & 255u);
  const float* srow = &Hm[((sc << 8) + skb) * 256];
  for (int kk = 0; kk < 256; kk += 16) {
    float4 a4;
    if (sr < ne) a4 = *(const float4*)&srow[kk + skc];
    else { a4.x = a4.y = a4.z = a4.w = 0.0f; }
    As[skc + 0][sr] = a4.x; As[skc + 1][sr] = a4.y;
    As[skc + 2][sr] = a4.z; As[skc + 3][sr] = a4.w;
#pragma unroll
    for (int i = 0; i < 4; i++) {
      int idx = tid + i * 256;
      int r = idx >> 6, c4 = idx & 63;
      *(float4*)&Bs[r][c4 * 4] = *(const float4*)&W[(kk + r) * 256 + c4 * 4];
    }
    __syncthreads();
#pragma unroll
    for (int kc = 0; kc < 16; kc++) {
      float4 a0  = *(const float4*)&As[kc][rg * 8];
      float4 a1  = *(const float4*)&As[kc][rg * 8 + 4];
      float4 blo = *(const float4*)&Bs[kc][cq * 4];
      float4 bhi = *(const float4*)&Bs[kc][128 + cq * 4];
      float a[8]  = {a0.x, a0.y, a0.z, a0.w, a1.x, a1.y, a1.z, a1.w};
      float bb[8] = {blo.x, blo.y, blo.z, blo.w, bhi.x, bhi.y, bhi.z, bhi.w};
#pragma unroll
      for (int rr = 0; rr < 8; rr++)
#pragma unroll
        for (int q = 0; q < 8; q++) acc[rr][q] += a[rr] * bb[q];
    }
    __syncthreads();
  }
#pragma unroll
  for (int rr = 0; rr < 8; rr++) {
    int e = rg * 8 + rr;
    if (e < ne) {
      unsigned en = ent[e];
      int t = (int)((en >> 9) & 511u), kb = (int)((en >> 18) & 255u);
      float* dst = &Gm[((t << 8) + kb) * 256];
      float4 lo = *(const float4*)&dst[cq * 4];
      float4 hi = *(const float4*)&dst[128 + cq * 4];
      lo.x += acc[rr][0]; lo.y += acc[rr][1]; lo.z += acc[rr][2]; lo.w += acc[rr][3];
      hi.x += acc[rr][4]; hi.y += acc[rr][5]; hi.z += acc[rr][6]; hi.w += acc[rr][7];
      *(float4*)&dst[cq * 4] = lo;
      *(float4*)&dst[128 + cq * 4] = hi;
    }
  }
}

// ---------------- K3: sequential combine chain, one wg per batch ----------------
// 512 threads: thread (j = tid&255, h = tid>>8) holds W_ch[1][h*128..+127][j]
// in VGPRs (launch_bounds(512,2)). Per chain step: only lgkmcnt-draining raw
// barriers (the Mm store and the prefetched next-step G-row stay in flight
// across barriers); G-row for step n+1 issued before step n's dot.
__global__ __launch_bounds__(512, 2) void k_seq(float* __restrict__ Mm,
                                                const float* __restrict__ Wch,
                                                const unsigned* __restrict__ ws) {
  int k = blockIdx.x;
  int tid = threadIdx.x;
  int j = tid & 255, h = tid >> 8;
  __shared__ __align__(16) float crow[256];
  __shared__ float partial[256];
  __shared__ int cached;
  if (tid == 0) cached = -1;
  float w[128];
  const float* W1 = Wch + D * D;
#pragma unroll
  for (int p = 0; p < 128; p++) w[p] = W1[(h * 128 + p) * 256 + j];
  int nw = (int)ws[WS_NW + k];
  const unsigned* work = ws + WS_WORK + k * 1024;
  float acc = 0.0f;
  __syncthreads();
  unsigned e = (nw > 0) ? work[0] : 0u;
  float nb = 0.0f;  // prefetched G-row value for the next `first` entry
  if (nw > 0 && ((e >> 19) & 1u) && h == 0)
    nb = Mm[(((int)(e & 511u) << 8) + k) * 256 + j];
  for (int n = 0; n < nw; n++) {
    unsigned cur = e;
    unsigned nxt = (n + 1 < nw) ? work[n + 1] : 0u;
    int t = (int)(cur & 511u), c = (int)((cur >> 9) & 511u);
    int wi = (int)((cur >> 18) & 1u);
    bool first = (cur >> 19) & 1u, last = (cur >> 20) & 1u, hasc = (cur >> 21) & 1u;
    if (first) acc = (h == 0) ? nb : 0.0f;     // consume prefetch
    float nb2 = 0.0f;                           // issue next prefetch early
    if ((n + 1 < nw) && ((nxt >> 19) & 1u) && h == 0)
      nb2 = Mm[(((int)(nxt & 511u) << 8) + k) * 256 + j];
    if (hasc) {
      if (c != cached) {
        // rare generic path: full drain so prior in-flight stores are visible
        asm volatile("s_waitcnt vmcnt(0) lgkmcnt(0)" ::: "memory");
        __builtin_amdgcn_s_barrier();
        __builtin_amdgcn_sched_barrier(0);
        if (tid < 256) crow[tid] = Mm[((c << 8) + k) * 256 + tid];
        if (tid == 0) cached = c;
        asm volatile("s_waitcnt vmcnt(0) lgkmcnt(0)" ::: "memory");
        __builtin_amdgcn_s_barrier();
        __builtin_amdgcn_sched_barrier(0);
      }
      if (wi == 1) {  // fast path: register-resident W_ch[1]
#pragma unroll
        for (int p = 0; p < 32; p++) {
          float4 c4 = ((const float4*)crow)[h * 32 + p];
          acc += c4.x * w[4 * p] + c4.y * w[4 * p + 1] +
                 c4.z * w[4 * p + 2] + c4.w * w[4 * p + 3];
        }
      } else {  // rare: stream W_ch[0] from L2
        const float* W0 = Wch;
#pragma unroll 8
        for (int p = 0; p < 128; p++)
          acc += crow[h * 128 + p] * W0[(h * 128 + p) * 256 + j];
      }
    }
    if (last) {
      if (h == 1) partial[j] = acc;
      __builtin_amdgcn_sched_barrier(0);
      asm volatile("s_waitcnt lgkmcnt(0)" ::: "memory");
      __builtin_amdgcn_s_barrier();               // no vmcnt drain
      __builtin_amdgcn_sched_barrier(0);
      if (h == 0) {
        float v = tanhf(acc + partial[j]);
        Mm[((t << 8) + k) * 256 + j] = v;          // fire-and-forget store
        crow[j] = v;
      }
      if (tid == 0) cached = t;
      __builtin_amdgcn_sched_barrier(0);
      asm volatile("s_waitcnt lgkmcnt(0)" ::: "memory");
      __builtin_amdgcn_s_barrier();               // no vmcnt drain
      __builtin_amdgcn_sched_barrier(0);
    }
    e = nxt; nb = nb2;
  }
}

// ---------------- K4: gather roots ----------------
__global__ __launch_bounds__(256) void k_root(const float* __restrict__ Mm,
                                              float* __restrict__ out,
                                              const unsigned* __restrict__ ws) {
  int k = blockIdx.x;
  unsigned r = ws[WS_ROOT + k];
  out[k * 256 + threadIdx.x] = Mm[(((int)r << 8) + k) * 256 + threadIdx.x];
}

extern "C" void kernel_launch(void* const* d_in, const int* in_sizes, int n_in,
                              void* d_out, int out_size, void* d_ws, size_t ws_size,
                              hipStream_t stream) {
  const float* X    = (const float*)d_in[0];
  const int*   AR   = (const int*)d_in[1];
  const float* Win  = (const float*)d_in[2];
  const float* Wch  = (const float*)d_in[3];
  const float* bias = (const float*)d_in[4];
  float* out = (float*)d_out;
  float* Mm  = out + B * D;  // memory region of output doubles as H/G scratch
  unsigned* ws = (unsigned*)d_ws;

  hipMemsetAsync(d_ws, 0, 512, stream);  // zero atomic counters
  k_stack<<<B, 256, 0, stream>>>(AR, ws);
  k_gemm_h<<<(T * B) / 64, 256, 0, stream>>>(X, Win, bias, AR, Mm);
  k_leafgemm<<<(T * B) / 64, 256, 0, stream>>>(Mm, Mm, Wch, ws + WS_L0, ws + WS_CNT + 0, 0);
  k_leafgemm<<<(T * B) / 64, 256, 0, stream>>>(Mm, Mm, Wch, ws + WS_L1, ws + WS_CNT + 1, 1);
  k_seq<<<B, 512, 0, stream>>>(Mm, Wch, ws);
  k_root<<<B, 256, 0, stream>>>(Mm, out, ws);
}

// Round 3
// 914.893 us; speedup vs baseline: 1.6887x; 1.1381x over previous
//
#include <hip/hip_runtime.h>
#include <hip/hip_bf16.h>

// TreeNet: T=512 nodes, B=256 batch, D=256 dim, BF=2 branching.
// Decomposition:
//   K0  stack simulation (int only) -> child lists / worklists
//   K1  H = inputs @ W_in + b; leaf rows (ar<=0) get tanh fused at store
//   K2a G[t] += H[leaf_child] @ W_ch[i]   (leaf rows already tanh'd by K1)
//   K3  sequential per-batch chain (restructured, see below)
//   K4  out[k] = memory[root[k], k]
//
// R3 diagnosis: k_seq was LDS-READ-PIPE bound, not FMA/remat bound.
//   353us / 254 steps = 3330 cyc/step; old structure = 256 ds_read_b128
//   broadcast instrs/step x ~12cyc regwrite = 3072 cyc. Every thread read
//   all 128 h-values with zero reuse (256 KB/step LDS delivery).
// R3 k_seq: thread = 4 columns x 32 p's (wave shares p-slice -> broadcast
//   reads, but each h value now feeds 8 FMAs). LDS h-traffic 256KB -> 64KB
//   per step. W_ch[1] fragment (128 VGPRs as 64x f2) pinned with empty
//   asm "+v" so the compiler cannot re-stream it from L2 per step.
//   crow double-buffered; barriers are lgkmcnt-only; `cached` is a uniform
//   register. FP summation regrouped (8 ordered 32-wide slice sums) --
//   few-ulp change, inside tolerance.

constexpr int T = 512, B = 256, D = 256;

typedef float f2 __attribute__((ext_vector_type(2)));
typedef float f4 __attribute__((ext_vector_type(4)));

// ws layout in u32 units
constexpr int WS_CNT  = 0;        // [2] atomic counters for leaf lists
constexpr int WS_ROOT = 16;       // [256]
constexpr int WS_NW   = 272;      // [256]
constexpr int WS_L0   = 1024;     // [131072] leaf-child entries, i=0
constexpr int WS_L1   = WS_L0 + T * B;     // [131072] i=1
constexpr int WS_WORK = WS_L1 + T * B;     // [256*1024] per-k combine worklist

// ---------------- K0: stack simulation ----------------
__global__ __launch_bounds__(256) void k_stack(const int* __restrict__ ar,
                                               unsigned* __restrict__ ws) {
  __shared__ int ar_l[T];
  __shared__ int S[1024];          // stack ring buffer (mask 1023), write-through
  __shared__ unsigned lbuf0[T];
  __shared__ unsigned lbuf1[T];
  __shared__ unsigned wbuf[1024];
  __shared__ int cnts[4];          // n0, n1, nw, root
  __shared__ unsigned base0, base1;

  int k = blockIdx.x;
  int tid = threadIdx.x;
  ar_l[tid]       = ar[tid * B + k];
  ar_l[tid + 256] = ar[(tid + 256) * B + k];
  S[tid] = 0; S[tid + 256] = 0; S[tid + 512] = 0; S[tid + 768] = 0;
  __syncthreads();

  if (tid == 0) {
    int ptr = 1;           // BF-1
    int top = 0, next = 0; // register cache of S[ptr], S[ptr-1]
    int n0 = 0, n1 = 0, nw = 0;
    for (int t = 0; t < T; t++) {
      int a = ar_l[t];
      int aa = a < 0 ? -a : a;
      unsigned cc[2]; int ncc = 0;
      if (a > 0) {
        int c0 = top;
        if (ar_l[c0] <= 0)
          lbuf0[n0++] = (unsigned)c0 | ((unsigned)t << 9) | ((unsigned)k << 18);
        else
          cc[ncc++] = (unsigned)c0;                 // child slot 0 -> W_ch[0]
        if (a > 1) {
          int c1 = next;
          if (ar_l[c1] <= 0)
            lbuf1[n1++] = (unsigned)c1 | ((unsigned)t << 9) | ((unsigned)k << 18);
          else
            cc[ncc++] = (unsigned)c1 | (1u << 18);  // child slot 1 -> W_ch[1]
        }
      }
      if (a >= 1) {  // combine node: K3 must finalize (tanh) it
        if (ncc == 0) {
          wbuf[nw++] = (unsigned)t | (1u << 19) | (1u << 20);
        } else {
          for (int e = 0; e < ncc; e++) {
            unsigned w = (unsigned)t | ((cc[e] & 511u) << 9) |
                         (((cc[e] >> 18) & 1u) << 18) | (1u << 21);
            if (e == 0) w |= (1u << 19);
            if (e == ncc - 1) w |= (1u << 20);
            wbuf[nw++] = w;
          }
        }
      }
      int pnew = ptr - aa + 1;
      if (a != -1) {
        S[pnew & 1023] = t;                 // write-through
        if (aa == 0)      { next = top; top = t; }
        else if (aa == 1) { top = t; }
        else              { top = t; next = S[(pnew - 1) & 1023]; } // refill
      }
      ptr = pnew;
    }
    cnts[0] = n0; cnts[1] = n1; cnts[2] = nw;
    cnts[3] = S[ptr & 1023];
    base0 = atomicAdd(ws + WS_CNT + 0, (unsigned)n0);
    base1 = atomicAdd(ws + WS_CNT + 1, (unsigned)n1);
  }
  __syncthreads();
  int n0 = cnts[0], n1 = cnts[1], nw = cnts[2];
  for (int i = tid; i < n0; i += 256) ws[WS_L0 + base0 + i] = lbuf0[i];
  for (int i = tid; i < n1; i += 256) ws[WS_L1 + base1 + i] = lbuf1[i];
  for (int i = tid; i < nw; i += 256) ws[WS_WORK + k * 1024 + i] = wbuf[i];
  if (tid == 0) { ws[WS_NW + k] = (unsigned)nw; ws[WS_ROOT + k] = (unsigned)cnts[3]; }
}

// ---------------- K1: H = X @ W_in + b  (+ fused leaf tanh) ----------------
// (frozen from R2 -- ran inside the 1041us total without spills)
__global__ __launch_bounds__(256) void k_gemm_h(const float* __restrict__ X,
                                                const float* __restrict__ W,
                                                const float* __restrict__ bias,
                                                const int* __restrict__ ar,
                                                float* __restrict__ Hm) {
  int row0 = blockIdx.x * 64;
  __shared__ __align__(16) float As[16][68];   // [k][row], 272B stride (16B-aligned)
  __shared__ __align__(16) float Bs[16][256];  // [k][col]
  __shared__ int lar[64];
  int tid = threadIdx.x;
  if (tid < 64) lar[tid] = ar[row0 + tid];     // row = t*B+k == flat ar index
  int cq = tid & 31, rg = tid >> 5;
  float acc[8][8];
  float4 b_lo = *(const float4*)&bias[cq * 4];
  float4 b_hi = *(const float4*)&bias[128 + cq * 4];
#pragma unroll
  for (int rr = 0; rr < 8; rr++) {
    acc[rr][0] = b_lo.x; acc[rr][1] = b_lo.y; acc[rr][2] = b_lo.z; acc[rr][3] = b_lo.w;
    acc[rr][4] = b_hi.x; acc[rr][5] = b_hi.y; acc[rr][6] = b_hi.z; acc[rr][7] = b_hi.w;
  }
  int sr = tid >> 2;           // staging row 0..63
  int skc = (tid & 3) * 4;     // staging k-offset
  for (int kk = 0; kk < 256; kk += 16) {
    float4 a4 = *(const float4*)&X[(row0 + sr) * 256 + kk + skc];
    As[skc + 0][sr] = a4.x; As[skc + 1][sr] = a4.y;
    As[skc + 2][sr] = a4.z; As[skc + 3][sr] = a4.w;
#pragma unroll
    for (int i = 0; i < 4; i++) {
      int idx = tid + i * 256;
      int r = idx >> 6, c4 = idx & 63;
      *(float4*)&Bs[r][c4 * 4] = *(const float4*)&W[(kk + r) * 256 + c4 * 4];
    }
    __syncthreads();
#pragma unroll
    for (int kc = 0; kc < 16; kc++) {
      float4 a0  = *(const float4*)&As[kc][rg * 8];       // broadcast b128
      float4 a1  = *(const float4*)&As[kc][rg * 8 + 4];
      float4 blo = *(const float4*)&Bs[kc][cq * 4];       // contiguous b128
      float4 bhi = *(const float4*)&Bs[kc][128 + cq * 4];
      float a[8]  = {a0.x, a0.y, a0.z, a0.w, a1.x, a1.y, a1.z, a1.w};
      float bb[8] = {blo.x, blo.y, blo.z, blo.w, bhi.x, bhi.y, bhi.z, bhi.w};
#pragma unroll
      for (int rr = 0; rr < 8; rr++)
#pragma unroll
        for (int q = 0; q < 8; q++) acc[rr][q] += a[rr] * bb[q];
    }
    __syncthreads();
  }
#pragma unroll
  for (int rr = 0; rr < 8; rr++) {
    int row = rg * 8 + rr;
    bool leaf = lar[row] <= 0;   // leaf (or ignore) node: finalize with tanh
    float4 lo, hi;
    lo.x = acc[rr][0]; lo.y = acc[rr][1]; lo.z = acc[rr][2]; lo.w = acc[rr][3];
    hi.x = acc[rr][4]; hi.y = acc[rr][5]; hi.z = acc[rr][6]; hi.w = acc[rr][7];
    if (leaf) {
      lo.x = tanhf(lo.x); lo.y = tanhf(lo.y); lo.z = tanhf(lo.z); lo.w = tanhf(lo.w);
      hi.x = tanhf(hi.x); hi.y = tanhf(hi.y); hi.z = tanhf(hi.z); hi.w = tanhf(hi.w);
    }
    float* dst = &Hm[(row0 + row) * 256];
    *(float4*)&dst[cq * 4] = lo;
    *(float4*)&dst[128 + cq * 4] = hi;
  }
}

// ---------------- K2a: gather-GEMM of leaf-child contributions ----------------
// (frozen from R2)
__global__ __launch_bounds__(256) void k_leafgemm(const float* __restrict__ Hm,
                                                  float* __restrict__ Gm,
                                                  const float* __restrict__ Wch,
                                                  const unsigned* __restrict__ list,
                                                  const unsigned* __restrict__ cntp,
                                                  int which) {
  unsigned cnt = *cntp;
  unsigned tile0 = blockIdx.x * 64;
  if (tile0 >= cnt) return;
  int ne = (int)min(64u, cnt - tile0);
  __shared__ unsigned ent[64];
  __shared__ __align__(16) float As[16][68];
  __shared__ __align__(16) float Bs[16][256];
  int tid = threadIdx.x;
  if (tid < 64) ent[tid] = (tid < ne) ? list[tile0 + tid] : 0u;
  __syncthreads();
  const float* W = Wch + which * (D * D);
  int cq = tid & 31, rg = tid >> 5;
  float acc[8][8];
#pragma unroll
  for (int rr = 0; rr < 8; rr++)
#pragma unroll
    for (int q = 0; q < 8; q++) acc[rr][q] = 0.0f;
  int sr = tid >> 2;
  int skc = (tid & 3) * 4;
  unsigned se = ent[sr];
  int sc = (int)(se & 511u), skb = (int)((se >> 18) & 255u);
  const float* srow = &Hm[((sc << 8) + skb) * 256];
  for (int kk = 0; kk < 256; kk += 16) {
    float4 a4;
    if (sr < ne) a4 = *(const float4*)&srow[kk + skc];
    else { a4.x = a4.y = a4.z = a4.w = 0.0f; }
    As[skc + 0][sr] = a4.x; As[skc + 1][sr] = a4.y;
    As[skc + 2][sr] = a4.z; As[skc + 3][sr] = a4.w;
#pragma unroll
    for (int i = 0; i < 4; i++) {
      int idx = tid + i * 256;
      int r = idx >> 6, c4 = idx & 63;
      *(float4*)&Bs[r][c4 * 4] = *(const float4*)&W[(kk + r) * 256 + c4 * 4];
    }
    __syncthreads();
#pragma unroll
    for (int kc = 0; kc < 16; kc++) {
      float4 a0  = *(const float4*)&As[kc][rg * 8];
      float4 a1  = *(const float4*)&As[kc][rg * 8 + 4];
      float4 blo = *(const float4*)&Bs[kc][cq * 4];
      float4 bhi = *(const float4*)&Bs[kc][128 + cq * 4];
      float a[8]  = {a0.x, a0.y, a0.z, a0.w, a1.x, a1.y, a1.z, a1.w};
      float bb[8] = {blo.x, blo.y, blo.z, blo.w, bhi.x, bhi.y, bhi.z, bhi.w};
#pragma unroll
      for (int rr = 0; rr < 8; rr++)
#pragma unroll
        for (int q = 0; q < 8; q++) acc[rr][q] += a[rr] * bb[q];
    }
    __syncthreads();
  }
#pragma unroll
  for (int rr = 0; rr < 8; rr++) {
    int e = rg * 8 + rr;
    if (e < ne) {
      unsigned en = ent[e];
      int t = (int)((en >> 9) & 511u), kb = (int)((en >> 18) & 255u);
      float* dst = &Gm[((t << 8) + kb) * 256];
      float4 lo = *(const float4*)&dst[cq * 4];
      float4 hi = *(const float4*)&dst[128 + cq * 4];
      lo.x += acc[rr][0]; lo.y += acc[rr][1]; lo.z += acc[rr][2]; lo.w += acc[rr][3];
      hi.x += acc[rr][4]; hi.y += acc[rr][5]; hi.z += acc[rr][6]; hi.w += acc[rr][7];
      *(float4*)&dst[cq * 4] = lo;
      *(float4*)&dst[128 + cq * 4] = hi;
    }
  }
}

// ---------------- K3: sequential combine chain, one wg per batch ----------------
// thread (cs = tid&63, ps = tid>>6): columns [4cs,4cs+4) x p-slice [32ps,32ps+32).
// Wave shares ps -> h reads are LDS broadcasts, each h value feeds 8 FMAs
// (4x less LDS delivery than the one-col-per-thread layout). W_ch[1] fragment
// pinned in 128 VGPRs via empty asm. Cross-slice reduce through partial[8][256].
__global__ __launch_bounds__(512, 2) void k_seq(float* __restrict__ Mm,
                                                const float* __restrict__ Wch,
                                                const unsigned* __restrict__ ws) {
  int k = blockIdx.x;
  int tid = threadIdx.x;
  int cs = tid & 63;         // column group: cols 4cs..4cs+3
  int ps = tid >> 6;         // p-slice [32ps, 32ps+32)  (== wave index)
  __shared__ __align__(16) float crow[2][256];    // double-buffered h vector
  __shared__ __align__(16) float partial[8][256]; // per-slice partial sums
  // W_ch[1] rows [32ps..+32), cols [4cs..+4) -> 64x f2 = 128 VGPRs
  f2 w01[32], w23[32];
  const float* W1 = Wch + D * D;
#pragma unroll
  for (int q = 0; q < 32; q++) {
    f4 wv = *(const f4*)&W1[(32 * ps + q) * 256 + 4 * cs];
    w01[q] = __builtin_shufflevector(wv, wv, 0, 1);
    w23[q] = __builtin_shufflevector(wv, wv, 2, 3);
  }
#pragma unroll
  for (int q = 0; q < 32; q++) {   // pin: forbid remat/re-load from L2 per step
    asm volatile("" : "+v"(w01[q]));
    asm volatile("" : "+v"(w23[q]));
  }
  int nw = (int)ws[WS_NW + k];
  const unsigned* work = ws + WS_WORK + k * 1024;
  int cached = -1;   // block-uniform -> plain register, no LDS round-trip
  int rb = 0;
  __syncthreads();
  unsigned e = (nw > 0) ? work[0] : 0u;
  float nb = 0.0f;   // prefetched G-row value for the next `first` entry
  if (nw > 0 && ((e >> 19) & 1u) && tid < 256)
    nb = Mm[(((int)(e & 511u) << 8) + k) * 256 + tid];
  f2 a01 = {0.0f, 0.0f}, a23 = {0.0f, 0.0f};
  for (int n = 0; n < nw; n++) {
    unsigned cur = e;
    unsigned nxt = (n + 1 < nw) ? work[n + 1] : 0u;
    int t = (int)(cur & 511u), c = (int)((cur >> 9) & 511u);
    int wi = (int)((cur >> 18) & 1u);
    bool first = (cur >> 19) & 1u, last = (cur >> 20) & 1u, hasc = (cur >> 21) & 1u;
    if (first) { a01 = (f2){0.0f, 0.0f}; a23 = (f2){0.0f, 0.0f}; }
    float nb2 = 0.0f;                          // issue next prefetch early
    if ((n + 1 < nw) && ((nxt >> 19) & 1u) && tid < 256)
      nb2 = Mm[(((int)(nxt & 511u) << 8) + k) * 256 + tid];
    if (hasc) {
      if (c != cached) {
        // rare generic path: full drain so prior in-flight stores are visible
        asm volatile("s_waitcnt vmcnt(0) lgkmcnt(0)" ::: "memory");
        __builtin_amdgcn_s_barrier();
        __builtin_amdgcn_sched_barrier(0);
        if (tid < 256) crow[rb][tid] = Mm[((c << 8) + k) * 256 + tid];
        cached = c;
        asm volatile("s_waitcnt vmcnt(0) lgkmcnt(0)" ::: "memory");
        __builtin_amdgcn_s_barrier();
        __builtin_amdgcn_sched_barrier(0);
      }
      const f4* hb = (const f4*)&crow[rb][32 * ps];
      if (wi == 1) {  // fast path: register-resident W_ch[1] fragment
#pragma unroll
        for (int q8 = 0; q8 < 8; q8++) {
          f4 h4 = hb[q8];
          f2 hx = {h4.x, h4.x}, hy = {h4.y, h4.y};
          f2 hz = {h4.z, h4.z}, hw = {h4.w, h4.w};
          a01 += hx * w01[4 * q8 + 0]; a23 += hx * w23[4 * q8 + 0];
          a01 += hy * w01[4 * q8 + 1]; a23 += hy * w23[4 * q8 + 1];
          a01 += hz * w01[4 * q8 + 2]; a23 += hz * w23[4 * q8 + 2];
          a01 += hw * w01[4 * q8 + 3]; a23 += hw * w23[4 * q8 + 3];
        }
      } else {        // rare: stream W_ch[0] from L2
        const float* W0 = Wch;
#pragma unroll 4
        for (int q = 0; q < 32; q++) {
          float hv = crow[rb][32 * ps + q];
          f4 wv = *(const f4*)&W0[(32 * ps + q) * 256 + 4 * cs];
          a01.x += hv * wv.x; a01.y += hv * wv.y;
          a23.x += hv * wv.z; a23.y += hv * wv.w;
        }
      }
    }
    if (last) {
      f4 pv = {a01.x, a01.y, a23.x, a23.y};
      *(f4*)&partial[ps][4 * cs] = pv;
      __builtin_amdgcn_sched_barrier(0);
      asm volatile("s_waitcnt lgkmcnt(0)" ::: "memory");
      __builtin_amdgcn_s_barrier();        // partials visible (no vmcnt drain)
      __builtin_amdgcn_sched_barrier(0);
      if (tid < 256) {
        float s = nb;
#pragma unroll
        for (int m = 0; m < 8; m++) s += partial[m][tid];
        float v = tanhf(s);
        crow[rb ^ 1][tid] = v;             // write-side buffer
        Mm[((t << 8) + k) * 256 + tid] = v; // fire-and-forget store
      }
      __builtin_amdgcn_sched_barrier(0);
      asm volatile("s_waitcnt lgkmcnt(0)" ::: "memory");
      __builtin_amdgcn_s_barrier();        // crow visible (no vmcnt drain)
      __builtin_amdgcn_sched_barrier(0);
      rb ^= 1;
      cached = t;
    }
    e = nxt; nb = nb2;
  }
}

// ---------------- K4: gather roots ----------------
__global__ __launch_bounds__(256) void k_root(const float* __restrict__ Mm,
                                              float* __restrict__ out,
                                              const unsigned* __restrict__ ws) {
  int k = blockIdx.x;
  unsigned r = ws[WS_ROOT + k];
  out[k * 256 + threadIdx.x] = Mm[(((int)r << 8) + k) * 256 + threadIdx.x];
}

extern "C" void kernel_launch(void* const* d_in, const int* in_sizes, int n_in,
                              void* d_out, int out_size, void* d_ws, size_t ws_size,
                              hipStream_t stream) {
  const float* X    = (const float*)d_in[0];
  const int*   AR   = (const int*)d_in[1];
  const float* Win  = (const float*)d_in[2];
  const float* Wch  = (const float*)d_in[3];
  const float* bias = (const float*)d_in[4];
  float* out = (float*)d_out;
  float* Mm  = out + B * D;  // memory region of output doubles as H/G scratch
  unsigned* ws = (unsigned*)d_ws;

  hipMemsetAsync(d_ws, 0, 512, stream);  // zero atomic counters
  k_stack<<<B, 256, 0, stream>>>(AR, ws);
  k_gemm_h<<<(T * B) / 64, 256, 0, stream>>>(X, Win, bias, AR, Mm);
  k_leafgemm<<<(T * B) / 64, 256, 0, stream>>>(Mm, Mm, Wch, ws + WS_L0, ws + WS_CNT + 0, 0);
  k_leafgemm<<<(T * B) / 64, 256, 0, stream>>>(Mm, Mm, Wch, ws + WS_L1, ws + WS_CNT + 1, 1);
  k_seq<<<B, 512, 0, stream>>>(Mm, Wch, ws);
  k_root<<<B, 256, 0, stream>>>(Mm, out, ws);
}